// Round 8
// baseline (225.980 us; speedup 1.0000x reference)
//
#include <hip/hip_runtime.h>

typedef unsigned int u32;
typedef unsigned long long u64;
typedef unsigned short u16;
typedef short bf16x8 __attribute__((ext_vector_type(8)));
typedef u16 u16x8 __attribute__((ext_vector_type(8)));
typedef float f32x4 __attribute__((ext_vector_type(4)));

// ---------------- helpers ----------------

__device__ __forceinline__ u16 f2bf(float f) {
  unsigned u = __float_as_uint(f);
  u += 0x7FFFu + ((u >> 16) & 1u);   // RNE
  return (u16)(u >> 16);
}

typedef const void __attribute__((address_space(1)))* gas_p;
typedef void __attribute__((address_space(3)))* las_p;

__device__ __forceinline__ void async_ld16(const void* g, void* l) {
  __builtin_amdgcn_global_load_lds((gas_p)g, (las_p)l, 16, 0, 0);
}

// ---------------- convert x -> bf16 ----------------

__global__ __launch_bounds__(256) void k_cvt_bf16(const float* __restrict__ in,
                                                  u16* __restrict__ out, int n8) {
  int i = blockIdx.x * 256 + threadIdx.x;
  if (i >= n8) return;
  const float4* p = (const float4*)in + (size_t)i * 2;
  float4 a = p[0], b = p[1];
  u16x8 o;
  o[0] = f2bf(a.x); o[1] = f2bf(a.y); o[2] = f2bf(a.z); o[3] = f2bf(a.w);
  o[4] = f2bf(b.x); o[5] = f2bf(b.y); o[6] = f2bf(b.z); o[7] = f2bf(b.w);
  *((u16x8*)out + i) = o;
}

// ---------------- transpose + convert W[K][N] -> Wt[N][K] bf16 ----------------

__global__ __launch_bounds__(256) void k_transpose_cvt(const float* __restrict__ in,
                                                       u16* __restrict__ out,
                                                       int R, int Ncols) {
  __shared__ u16 t[32][33];
  int tx = threadIdx.x, ty = threadIdx.y;
  int c0 = blockIdx.x * 32, r0 = blockIdx.y * 32;
#pragma unroll
  for (int j = 0; j < 32; j += 8)
    t[ty + j][tx] = f2bf(in[(size_t)(r0 + ty + j) * Ncols + c0 + tx]);
  __syncthreads();
#pragma unroll
  for (int j = 0; j < 32; j += 8)
    out[(size_t)(c0 + ty + j) * R + r0 + tx] = t[tx][ty + j];
}

// ---------------- 256^2 bf16 GEMM (R4 schedule, best measured) ----------------

#define STAGE_A2(h_, src_, dd_) do {                                       \
    const u16* g_ = (src_) + (size_t)(h_) * 128 * KK;                      \
    u16* s_ = lds + (dd_) * 16384 + (((h_) * 128 + w * 16) << 6);          \
    async_ld16(g_, s_);                                                    \
    async_ld16(g_ + 8 * (size_t)KK, s_ + 512);                             \
  } while (0)

#define STAGE_B2(h_, src_, dd_) do {                                       \
    const u16* g_ = (src_) + (size_t)(h_) * 128 * KK;                      \
    u16* s_ = lds + 32768 + (dd_) * 16384 + (((h_) * 128 + w * 16) << 6);  \
    async_ld16(g_, s_);                                                    \
    async_ld16(g_ + 8 * (size_t)KK, s_ + 512);                             \
  } while (0)

// 16 MFMA: ks-outer -> 8 independent MFMAs between dependent pairs
#define MQUAD(M0, N0)                                                      \
    _Pragma("unroll") for (int ks = 0; ks < 2; ++ks)                       \
    _Pragma("unroll") for (int mm = 0; mm < 4; ++mm)                       \
    _Pragma("unroll") for (int nn = 0; nn < 2; ++nn)                       \
      acc[(M0) + mm][(N0) + nn] = __builtin_amdgcn_mfma_f32_16x16x32_bf16( \
          a[(M0) + mm][ks], b[(N0) + nn][ks], acc[(M0) + mm][(N0) + nn], 0, 0, 0);

#define TBX(d_, bS_, aS_)                                                  \
  {                                                                        \
    const int doA = (d_) * 16384, doB = 32768 + (d_) * 16384;              \
    _Pragma("unroll") for (int f = 0; f < 4; ++f) {                        \
      a[f][0] = *(const bf16x8*)(lds + doA + rAoff + f * 1024 + c0);       \
      a[f][1] = *(const bf16x8*)(lds + doA + rAoff + f * 1024 + c1);       \
    }                                                                      \
    _Pragma("unroll") for (int f = 0; f < 2; ++f) {                        \
      b[f][0] = *(const bf16x8*)(lds + doB + rBoff + f * 1024 + c0);       \
      b[f][1] = *(const bf16x8*)(lds + doB + rBoff + f * 1024 + c1);       \
    }                                                                      \
    STAGE_B2(0, bS_, (d_) ^ 1);                                            \
    asm volatile("s_waitcnt lgkmcnt(8)");                                  \
    __builtin_amdgcn_s_barrier();                                          \
    asm volatile("s_waitcnt lgkmcnt(0)");                                  \
    __builtin_amdgcn_s_setprio(1);                                         \
    MQUAD(0, 0)                                                            \
    __builtin_amdgcn_s_setprio(0);                                         \
    __builtin_amdgcn_s_barrier();                                          \
    _Pragma("unroll") for (int f = 4; f < 8; ++f) {                        \
      a[f][0] = *(const bf16x8*)(lds + doA + rAoff + f * 1024 + c0);       \
      a[f][1] = *(const bf16x8*)(lds + doA + rAoff + f * 1024 + c1);       \
    }                                                                      \
    STAGE_B2(1, bS_, (d_) ^ 1);                                            \
    __builtin_amdgcn_s_barrier();                                          \
    asm volatile("s_waitcnt lgkmcnt(0)");                                  \
    __builtin_amdgcn_s_setprio(1);                                         \
    MQUAD(4, 0)                                                            \
    __builtin_amdgcn_s_setprio(0);                                         \
    __builtin_amdgcn_s_barrier();                                          \
    _Pragma("unroll") for (int f = 2; f < 4; ++f) {                        \
      b[f][0] = *(const bf16x8*)(lds + doB + rBoff + f * 1024 + c0);       \
      b[f][1] = *(const bf16x8*)(lds + doB + rBoff + f * 1024 + c1);       \
    }                                                                      \
    STAGE_A2(0, aS_, (d_));                                                \
    __builtin_amdgcn_s_barrier();                                          \
    asm volatile("s_waitcnt lgkmcnt(0)");                                  \
    __builtin_amdgcn_s_setprio(1);                                         \
    MQUAD(4, 2)                                                            \
    __builtin_amdgcn_s_setprio(0);                                         \
    __builtin_amdgcn_s_barrier();                                          \
    STAGE_A2(1, aS_, (d_));                                                \
    __builtin_amdgcn_s_setprio(1);                                         \
    MQUAD(0, 2)                                                            \
    __builtin_amdgcn_s_setprio(0);                                         \
    asm volatile("s_waitcnt vmcnt(4)");                                    \
    __builtin_amdgcn_s_barrier();                                          \
  }

#define EPI(PM0, PN0) do {                                                      \
    int ccol0 = (PN0) + wn * 64 + (lane & 15);                                  \
    float bv0 = bias[ccol0], bv1 = bias[ccol0 + 16];                            \
    float bv2 = bias[ccol0 + 32], bv3 = bias[ccol0 + 48];                       \
    size_t crow0 = (size_t)((PM0) + wm * 128 + ((lane >> 4) << 2));             \
    _Pragma("unroll") for (int m = 0; m < 8; ++m)                               \
    _Pragma("unroll") for (int reg = 0; reg < 4; ++reg) {                       \
      size_t ro = (crow0 + m * 16 + reg) * (size_t)N + ccol0;                   \
      float v0 = acc[m][0][reg] + bv0, v1 = acc[m][1][reg] + bv1;               \
      float v2 = acc[m][2][reg] + bv2, v3 = acc[m][3][reg] + bv3;               \
      if (OUT_BF16) {                                                           \
        ((u16*)Cout)[ro] = f2bf(v0); ((u16*)Cout)[ro + 16] = f2bf(v1);          \
        ((u16*)Cout)[ro + 32] = f2bf(v2); ((u16*)Cout)[ro + 48] = f2bf(v3);     \
      } else {                                                                  \
        ((float*)Cout)[ro] = v0; ((float*)Cout)[ro + 16] = v1;                  \
        ((float*)Cout)[ro + 32] = v2; ((float*)Cout)[ro + 48] = v3;             \
      }                                                                         \
    }                                                                           \
  } while (0)

#define TILE_COORD(tt, mm0, nn0) do {                                           \
    int q_ = nwg >> 3, r_ = nwg & 7, x_ = (tt) & 7, loc_ = (tt) >> 3;           \
    int swz_ = (x_ < r_ ? x_ * (q_ + 1) : r_ * (q_ + 1) + (x_ - r_) * q_) + loc_;\
    mm0 = (swz_ / nbn) << 8; nn0 = (swz_ % nbn) << 8;                           \
  } while (0)

#define ZERO_ACC do {                                                           \
    _Pragma("unroll") for (int m = 0; m < 8; ++m)                               \
    _Pragma("unroll") for (int n = 0; n < 4; ++n)                               \
      acc[m][n] = (f32x4){0.f, 0.f, 0.f, 0.f};                                  \
  } while (0)

template <int OUT_BF16, int KK>
__global__ __launch_bounds__(512, 2) void k_gemm8(const u16* __restrict__ A,
                                                  const u16* __restrict__ Bt,
                                                  const float* __restrict__ bias,
                                                  void* __restrict__ Cout,
                                                  int M, int N) {
  extern __shared__ u16 lds[];
  const int NT = KK / 64;

  int nbn = N >> 8, nbm = M >> 8, nwg = nbm * nbn;
  int tid = threadIdx.x;
  int w = tid >> 6, lane = tid & 63;
  int wm = w >> 2, wn = w & 3;

  int rAoff = (wm * 128 + (lane & 15)) << 6;
  int rBoff = (wn * 64 + (lane & 15)) << 6;
  int hi8 = (lane >> 4) << 3, key8 = (lane & 7) << 3;
  int c0 = hi8 ^ key8;
  int c1 = (32 | hi8) ^ key8;
  int rowoff = w * 16 + (lane >> 3);
  int soff = ((lane & 7) ^ (lane >> 3)) << 3;

  bf16x8 a[8][2], b[4][2];
  f32x4 acc[8][4];

  int t = blockIdx.x;
  int m0, n0;
  TILE_COORD(t, m0, n0);
  const u16* pAg = A + (size_t)(m0 + rowoff) * KK + soff;
  const u16* pBg = Bt + (size_t)(n0 + rowoff) * KK + soff;

  // prologue: A(0),B(0) -> buf0; A(1) -> buf1 (left in flight)
  STAGE_A2(0, pAg, 0); STAGE_A2(1, pAg, 0);
  STAGE_B2(0, pBg, 0); STAGE_B2(1, pBg, 0);
  STAGE_A2(0, pAg + 64, 1); STAGE_A2(1, pAg + 64, 1);
  asm volatile("s_waitcnt vmcnt(4)");
  __builtin_amdgcn_s_barrier();
  ZERO_ACC;

  for (;;) {
    int tn = t + gridDim.x;
    bool last = tn >= nwg;
    const u16 *pAgN, *pBgN;
    int m0N = m0, n0N = n0;
    if (last) {                 // dummy: re-stage own tile start (L2-hot)
      pAgN = pAg; pBgN = pBg;
    } else {
      TILE_COORD(tn, m0N, n0N);
      pAgN = A + (size_t)(m0N + rowoff) * KK + soff;
      pBgN = Bt + (size_t)(n0N + rowoff) * KK + soff;
    }

    for (int k = 0; k < NT; k += 2) {
      const u16* bS1 = pBg + (k + 1) * 64;   // k+1 <= NT-1 always
      const u16* aS2 = (k + 2 < NT) ? pAg + (k + 2) * 64 : pAgN + (k + 2 - NT) * 64;
      TBX(0, bS1, aS2)
      const u16* bS2 = (k + 2 < NT) ? pBg + (k + 2) * 64 : pBgN + (k + 2 - NT) * 64;
      const u16* aS3 = (k + 3 < NT) ? pAg + (k + 3) * 64 : pAgN + (k + 3 - NT) * 64;
      TBX(1, bS2, aS3)
    }

    EPI(m0, n0);
    if (last) break;
    t = tn; m0 = m0N; n0 = n0N; pAg = pAgN; pBg = pBgN;
    ZERO_ACC;
  }
  asm volatile("s_waitcnt vmcnt(0) lgkmcnt(0)");  // drain dummy LDS-DMA
}

// ---------------- block-diagonal attention v4 ----------------
// 1024 WGs (b,h,blk); 1024 threads = 16 waves, 16 q-rows/wave -> full 256 q.
// K/V staged ONCE: waves 0-7 stage K (async, pre-swizzled), waves 8-15
// stage V^T (vectorized ds_write_b64). Per-wave compute identical to attn3.

__global__ __launch_bounds__(1024, 4) void k_attn4(const u16* __restrict__ qkv,
                                                   u16* __restrict__ o) {
  __shared__ u16 ldsK[256 * 64];   // swizzled K rows
  __shared__ u16 ldsV[64 * 256];   // V^T [d][t] swizzled

  int bid = blockIdx.x;
  int g = ((bid & 7) << 7) | (bid >> 3);   // nwg = 1024, bijective XCD swizzle
  int blk = g & 15, h = (g >> 4) & 15, b = g >> 8;

  int tid = threadIdx.x;
  int w = tid >> 6, lane = tid & 63;
  int hgrp = lane >> 4;
  size_t rowb = ((size_t)(b * 4096 + blk * 256)) * 3072 + (size_t)h * 192;

  // Q fragment (B-operand; col = lane&15 = q-in-set, k = d contiguous 8)
  int qrow = w * 16 + (lane & 15);
  const u16* qp = qkv + rowb + (size_t)qrow * 3072 + hgrp * 8;
  bf16x8 qf0 = *(const bf16x8*)(qp);
  bf16x8 qf1 = *(const bf16x8*)(qp + 32);

  if (w < 8) {
    // ---- waves 0-7: stage K (async, pre-swizzled source) ----
#pragma unroll
    for (int it = 0; it < 4; ++it) {
      int trow = it * 64 + (tid >> 3);
      const u16* ksrc = qkv + rowb + (size_t)trow * 3072 + 64 +
                        (((lane & 7) ^ (lane >> 3)) << 3);
      async_ld16(ksrc, ldsK + (it * 64 + w * 8) * 64);
    }
  } else {
    // ---- waves 8-15: stage V^T vectorized: thread = (4 t) x (8 d) ----
    int t512 = tid - 512;
    int tg = t512 >> 3, d0 = (t512 & 7) << 3;
    const u16* vsrc = qkv + rowb + (size_t)(4 * tg) * 3072 + 128 + d0;
    union { uint4 v; u16 s[8]; } r0, r1, r2, r3;
    r0.v = *(const uint4*)(vsrc);
    r1.v = *(const uint4*)(vsrc + 3072);
    r2.v = *(const uint4*)(vsrc + 6144);
    r3.v = *(const uint4*)(vsrc + 9216);
    int gb = ((tg >> 1) << 4) + ((tg & 1) << 3);   // byte col of 4-t group
#pragma unroll
    for (int c = 0; c < 8; ++c) {
      int d = d0 + c;
      int key = (((d & 7) ^ ((d >> 3) & 7)) & 7) << 4;
      u64 pack = (u64)r0.s[c] | ((u64)r1.s[c] << 16) |
                 ((u64)r2.s[c] << 32) | ((u64)r3.s[c] << 48);
      *(u64*)((char*)ldsV + d * 512 + ((gb & ~15) ^ key) + (gb & 8)) = pack;
    }
  }
  __syncthreads();

  // ---- S^T = K Q : acc[ct] rows t=ct*16+4h'+reg, col q=lane&15 ----
  f32x4 acc0[16] = {};
  int cb = hgrp << 4;
#pragma unroll
  for (int ct = 0; ct < 16; ++ct) {
    int krow = ct * 16 + (lane & 15);
    const char* kb = (const char*)ldsK + krow * 128;
    int key = (krow & 7) << 4;
    bf16x8 k0 = *(const bf16x8*)(kb + (cb ^ key));
    bf16x8 k1 = *(const bf16x8*)(kb + ((64 + cb) ^ key));
    acc0[ct] = __builtin_amdgcn_mfma_f32_16x16x32_bf16(k0, qf0, acc0[ct], 0, 0, 0);
    acc0[ct] = __builtin_amdgcn_mfma_f32_16x16x32_bf16(k1, qf1, acc0[ct], 0, 0, 0);
  }

  // ---- softmax over t (in-lane 64 + xor16 + xor32) ----
  const float SC = 0.125f * 1.44269504f;
  float rden0;
  {
    float mx = -1e30f;
#pragma unroll
    for (int ct = 0; ct < 16; ++ct)
#pragma unroll
      for (int rg = 0; rg < 4; ++rg) mx = fmaxf(mx, acc0[ct][rg]);
    mx = fmaxf(mx, __shfl_xor(mx, 16));
    mx = fmaxf(mx, __shfl_xor(mx, 32));
    float s = 0.f;
#pragma unroll
    for (int ct = 0; ct < 16; ++ct)
#pragma unroll
      for (int rg = 0; rg < 4; ++rg) {
        float p = exp2f((acc0[ct][rg] - mx) * SC);
        acc0[ct][rg] = p;
        s += p;
      }
    s += __shfl_xor(s, 16);
    s += __shfl_xor(s, 32);
    rden0 = 1.f / s;
  }

  // ---- O = P V  (inline P-conversion per kt) ----
  int s1 = (lane & 15) + ((lane >> 4) & 1) * 32;
  int s2 = s1 + 16;
  bool lo = (lane < 32);
  f32x4 oa[4] = {};
#pragma unroll
  for (int kt = 0; kt < 8; ++kt) {
    u32 wA0, wB0, wA1, wB1;
    asm("v_cvt_pk_bf16_f32 %0, %1, %2" : "=v"(wA0)
        : "v"(acc0[2 * kt][0]), "v"(acc0[2 * kt][1]));
    asm("v_cvt_pk_bf16_f32 %0, %1, %2" : "=v"(wB0)
        : "v"(acc0[2 * kt][2]), "v"(acc0[2 * kt][3]));
    asm("v_cvt_pk_bf16_f32 %0, %1, %2" : "=v"(wA1)
        : "v"(acc0[2 * kt + 1][0]), "v"(acc0[2 * kt + 1][1]));
    asm("v_cvt_pk_bf16_f32 %0, %1, %2" : "=v"(wB1)
        : "v"(acc0[2 * kt + 1][2]), "v"(acc0[2 * kt + 1][3]));
    u32 t0a = (u32)__shfl((int)wA0, s1), t0b = (u32)__shfl((int)wA1, s1);
    u32 t1a = (u32)__shfl((int)wB0, s1), t1b = (u32)__shfl((int)wB1, s1);
    u32 t2a = (u32)__shfl((int)wA0, s2), t2b = (u32)__shfl((int)wA1, s2);
    u32 t3a = (u32)__shfl((int)wB0, s2), t3b = (u32)__shfl((int)wB1, s2);
    union { u32 w[4]; bf16x8 v; } pu;
    pu.w[0] = lo ? t0a : t0b;
    pu.w[1] = lo ? t1a : t1b;
    pu.w[2] = lo ? t2a : t2b;
    pu.w[3] = lo ? t3a : t3b;
    bf16x8 pa = pu.v;
    int vkb = 2 * (kt * 32 + hgrp * 8);
#pragma unroll
    for (int nt = 0; nt < 4; ++nt) {
      int vd = nt * 16 + (lane & 15);
      int key = (((vd & 7) ^ ((vd >> 3) & 7)) & 7) << 4;
      bf16x8 vf = *(const bf16x8*)((char*)ldsV + vd * 512 + (vkb ^ key));
      oa[nt] = __builtin_amdgcn_mfma_f32_16x16x32_bf16(pa, vf, oa[nt], 0, 0, 0);
    }
  }

  // ---- epilogue: rows q = 4*hgrp+reg (within wave's 16), col d ----
  float rd0[4];
#pragma unroll
  for (int rg = 0; rg < 4; ++rg) rd0[rg] = __shfl(rden0, 4 * hgrp + rg, 16);
  size_t ob = ((size_t)(b * 4096 + blk * 256 + w * 16)) * 1024 + (size_t)h * 64;
#pragma unroll
  for (int nt = 0; nt < 4; ++nt)
#pragma unroll
    for (int rg = 0; rg < 4; ++rg) {
      int col = nt * 16 + (lane & 15);
      o[ob + (size_t)(4 * hgrp + rg) * 1024 + col] = f2bf(oa[nt][rg] * rd0[rg]);
    }
}

// ---------------- launch ----------------

extern "C" void kernel_launch(void* const* d_in, const int* in_sizes, int n_in,
                              void* d_out, int out_size, void* d_ws, size_t ws_size,
                              hipStream_t stream) {
  (void)in_sizes; (void)n_in; (void)out_size; (void)ws_size;
  const float* x = (const float*)d_in[0];
  const float* Wqkv = (const float*)d_in[1];
  const float* bqkv = (const float*)d_in[2];
  const float* Wout = (const float*)d_in[3];
  const float* bout = (const float*)d_in[4];
  float* out = (float*)d_out;

  char* ws = (char*)d_ws;
  u16* xb    = (u16*)(ws + 0);
  u16* wqkvT = (u16*)(ws + 33554432);
  u16* woT   = (u16*)(ws + 39845888);
  u16* qkv   = (u16*)(ws + 41943040);
  u16* ob    = (u16*)(ws + 142606336);

  hipFuncSetAttribute(reinterpret_cast<const void*>(&k_gemm8<1, 1024>),
                      hipFuncAttributeMaxDynamicSharedMemorySize, 131072);
  hipFuncSetAttribute(reinterpret_cast<const void*>(&k_gemm8<0, 1024>),
                      hipFuncAttributeMaxDynamicSharedMemorySize, 131072);

  k_cvt_bf16<<<8192, 256, 0, stream>>>(x, xb, 16384 * 1024 / 8);
  k_transpose_cvt<<<dim3(96, 32), dim3(32, 8), 0, stream>>>(Wqkv, wqkvT, 1024, 3072);
  k_transpose_cvt<<<dim3(32, 32), dim3(32, 8), 0, stream>>>(Wout, woT, 1024, 1024);

  // qkv = x @ Wqkv + bqkv (bf16 out): 768 tiles, persistent over 256 WGs
  k_gemm8<1, 1024><<<256, 512, 131072, stream>>>(xb, wqkvT, bqkv, qkv, 16384, 3072);

  // block-diagonal attention: one 1024-thread WG per (b,h,blk)
  k_attn4<<<1024, 1024, 0, stream>>>(qkv, ob);

  // out = o @ Wout + bout (fp32 out): 256 tiles
  k_gemm8<0, 1024><<<256, 512, 131072, stream>>>(ob, woT, bout, out, 16384, 1024);
}

// Round 9
// 217.031 us; speedup vs baseline: 1.0412x; 1.0412x over previous
//
#include <hip/hip_runtime.h>

typedef unsigned int u32;
typedef unsigned long long u64;
typedef unsigned short u16;
typedef short bf16x8 __attribute__((ext_vector_type(8)));
typedef u16 u16x8 __attribute__((ext_vector_type(8)));
typedef float f32x4 __attribute__((ext_vector_type(4)));

// ---------------- helpers ----------------

__device__ __forceinline__ u16 f2bf(float f) {
  unsigned u = __float_as_uint(f);
  u += 0x7FFFu + ((u >> 16) & 1u);   // RNE
  return (u16)(u >> 16);
}

typedef const void __attribute__((address_space(1)))* gas_p;
typedef void __attribute__((address_space(3)))* las_p;

__device__ __forceinline__ void async_ld16(const void* g, void* l) {
  __builtin_amdgcn_global_load_lds((gas_p)g, (las_p)l, 16, 0, 0);
}

// ---------------- fused prep: x->bf16, Wqkv^T->bf16, Wout^T->bf16 ----------------
// blocks [0,8192): cvt x (2097152 chunks of 8)
// blocks [8192,11264): transpose Wqkv (96x32 tiles)
// blocks [11264,12288): transpose Wout (32x32 tiles)

__global__ __launch_bounds__(256) void k_prep(const float* __restrict__ x,
                                              u16* __restrict__ xb,
                                              const float* __restrict__ Wqkv,
                                              u16* __restrict__ wqkvT,
                                              const float* __restrict__ Wout,
                                              u16* __restrict__ woT) {
  __shared__ u16 tsh[32][33];
  int bid = blockIdx.x;
  int tid = threadIdx.x;

  if (bid < 8192) {
    int i = bid * 256 + tid;
    const float4* p = (const float4*)x + (size_t)i * 2;
    float4 a = p[0], b = p[1];
    u16x8 o;
    o[0] = f2bf(a.x); o[1] = f2bf(a.y); o[2] = f2bf(a.z); o[3] = f2bf(a.w);
    o[4] = f2bf(b.x); o[5] = f2bf(b.y); o[6] = f2bf(b.z); o[7] = f2bf(b.w);
    *((u16x8*)xb + i) = o;
    return;
  }

  const float* in;
  u16* out;
  int R, Ncols, bx, by;
  if (bid < 11264) {
    int t = bid - 8192;
    in = Wqkv; out = wqkvT; R = 1024; Ncols = 3072;
    bx = t % 96; by = t / 96;
  } else {
    int t = bid - 11264;
    in = Wout; out = woT; R = 1024; Ncols = 1024;
    bx = t & 31; by = t >> 5;
  }
  int tx = tid & 31, ty = tid >> 5;
  int c0 = bx * 32, r0 = by * 32;
#pragma unroll
  for (int j = 0; j < 32; j += 8)
    tsh[ty + j][tx] = f2bf(in[(size_t)(r0 + ty + j) * Ncols + c0 + tx]);
  __syncthreads();
#pragma unroll
  for (int j = 0; j < 32; j += 8)
    out[(size_t)(c0 + ty + j) * R + r0 + tx] = tsh[tx][ty + j];
}

// ---------------- 256^2 bf16 GEMM (R4 schedule, merged P3') ----------------

#define STAGE_A2(h_, src_, dd_) do {                                       \
    const u16* g_ = (src_) + (size_t)(h_) * 128 * KK;                      \
    u16* s_ = lds + (dd_) * 16384 + (((h_) * 128 + w * 16) << 6);          \
    async_ld16(g_, s_);                                                    \
    async_ld16(g_ + 8 * (size_t)KK, s_ + 512);                             \
  } while (0)

#define STAGE_B2(h_, src_, dd_) do {                                       \
    const u16* g_ = (src_) + (size_t)(h_) * 128 * KK;                      \
    u16* s_ = lds + 32768 + (dd_) * 16384 + (((h_) * 128 + w * 16) << 6);  \
    async_ld16(g_, s_);                                                    \
    async_ld16(g_ + 8 * (size_t)KK, s_ + 512);                             \
  } while (0)

// 16 MFMA: ks-outer -> 8 independent MFMAs between dependent pairs
#define MQUAD(M0, N0)                                                      \
    _Pragma("unroll") for (int ks = 0; ks < 2; ++ks)                       \
    _Pragma("unroll") for (int mm = 0; mm < 4; ++mm)                       \
    _Pragma("unroll") for (int nn = 0; nn < 2; ++nn)                       \
      acc[(M0) + mm][(N0) + nn] = __builtin_amdgcn_mfma_f32_16x16x32_bf16( \
          a[(M0) + mm][ks], b[(N0) + nn][ks], acc[(M0) + mm][(N0) + nn], 0, 0, 0);

#define TBX(d_, bS_, aS_)                                                  \
  {                                                                        \
    const int doA = (d_) * 16384, doB = 32768 + (d_) * 16384;              \
    /* P1: read a0-3, b0-1; stage B(k+1) h0 */                             \
    _Pragma("unroll") for (int f = 0; f < 4; ++f) {                        \
      a[f][0] = *(const bf16x8*)(lds + doA + rAoff + f * 1024 + c0);       \
      a[f][1] = *(const bf16x8*)(lds + doA + rAoff + f * 1024 + c1);       \
    }                                                                      \
    _Pragma("unroll") for (int f = 0; f < 2; ++f) {                        \
      b[f][0] = *(const bf16x8*)(lds + doB + rBoff + f * 1024 + c0);       \
      b[f][1] = *(const bf16x8*)(lds + doB + rBoff + f * 1024 + c1);       \
    }                                                                      \
    STAGE_B2(0, bS_, (d_) ^ 1);                                            \
    asm volatile("s_waitcnt lgkmcnt(8)");                                  \
    __builtin_amdgcn_s_barrier();                                          \
    asm volatile("s_waitcnt lgkmcnt(0)");                                  \
    __builtin_amdgcn_s_setprio(1);                                         \
    MQUAD(0, 0)                                                            \
    __builtin_amdgcn_s_setprio(0);                                         \
    __builtin_amdgcn_s_barrier();                                          \
    /* P2: read a4-7; stage B(k+1) h1 */                                   \
    _Pragma("unroll") for (int f = 4; f < 8; ++f) {                        \
      a[f][0] = *(const bf16x8*)(lds + doA + rAoff + f * 1024 + c0);       \
      a[f][1] = *(const bf16x8*)(lds + doA + rAoff + f * 1024 + c1);       \
    }                                                                      \
    STAGE_B2(1, bS_, (d_) ^ 1);                                            \
    __builtin_amdgcn_s_barrier();                                          \
    asm volatile("s_waitcnt lgkmcnt(0)");                                  \
    __builtin_amdgcn_s_setprio(1);                                         \
    MQUAD(4, 0)                                                            \
    __builtin_amdgcn_s_setprio(0);                                         \
    __builtin_amdgcn_s_barrier();                                          \
    /* P3': read b2-3; stage A(k+2) h0+h1; 32-MFMA tail; counted vmcnt */  \
    _Pragma("unroll") for (int f = 2; f < 4; ++f) {                        \
      b[f][0] = *(const bf16x8*)(lds + doB + rBoff + f * 1024 + c0);       \
      b[f][1] = *(const bf16x8*)(lds + doB + rBoff + f * 1024 + c1);       \
    }                                                                      \
    STAGE_A2(0, aS_, (d_));                                                \
    STAGE_A2(1, aS_, (d_));                                                \
    __builtin_amdgcn_s_barrier();                                          \
    asm volatile("s_waitcnt lgkmcnt(0)");                                  \
    __builtin_amdgcn_s_setprio(1);                                         \
    MQUAD(4, 2)                                                            \
    MQUAD(0, 2)                                                            \
    __builtin_amdgcn_s_setprio(0);                                         \
    asm volatile("s_waitcnt vmcnt(4)");                                    \
    __builtin_amdgcn_s_barrier();                                          \
  }

#define EPI(PM0, PN0) do {                                                      \
    int ccol0 = (PN0) + wn * 64 + (lane & 15);                                  \
    float bv0 = bias[ccol0], bv1 = bias[ccol0 + 16];                            \
    float bv2 = bias[ccol0 + 32], bv3 = bias[ccol0 + 48];                       \
    size_t crow0 = (size_t)((PM0) + wm * 128 + ((lane >> 4) << 2));             \
    _Pragma("unroll") for (int m = 0; m < 8; ++m)                               \
    _Pragma("unroll") for (int reg = 0; reg < 4; ++reg) {                       \
      size_t ro = (crow0 + m * 16 + reg) * (size_t)N + ccol0;                   \
      float v0 = acc[m][0][reg] + bv0, v1 = acc[m][1][reg] + bv1;               \
      float v2 = acc[m][2][reg] + bv2, v3 = acc[m][3][reg] + bv3;               \
      if (OUT_BF16) {                                                           \
        ((u16*)Cout)[ro] = f2bf(v0); ((u16*)Cout)[ro + 16] = f2bf(v1);          \
        ((u16*)Cout)[ro + 32] = f2bf(v2); ((u16*)Cout)[ro + 48] = f2bf(v3);     \
      } else {                                                                  \
        ((float*)Cout)[ro] = v0; ((float*)Cout)[ro + 16] = v1;                  \
        ((float*)Cout)[ro + 32] = v2; ((float*)Cout)[ro + 48] = v3;             \
      }                                                                         \
    }                                                                           \
  } while (0)

#define TILE_COORD(tt, mm0, nn0) do {                                           \
    int q_ = nwg >> 3, r_ = nwg & 7, x_ = (tt) & 7, loc_ = (tt) >> 3;           \
    int swz_ = (x_ < r_ ? x_ * (q_ + 1) : r_ * (q_ + 1) + (x_ - r_) * q_) + loc_;\
    mm0 = (swz_ / nbn) << 8; nn0 = (swz_ % nbn) << 8;                           \
  } while (0)

#define ZERO_ACC do {                                                           \
    _Pragma("unroll") for (int m = 0; m < 8; ++m)                               \
    _Pragma("unroll") for (int n = 0; n < 4; ++n)                               \
      acc[m][n] = (f32x4){0.f, 0.f, 0.f, 0.f};                                  \
  } while (0)

template <int OUT_BF16, int KK>
__global__ __launch_bounds__(512, 2) void k_gemm8(const u16* __restrict__ A,
                                                  const u16* __restrict__ Bt,
                                                  const float* __restrict__ bias,
                                                  void* __restrict__ Cout,
                                                  int M, int N) {
  extern __shared__ u16 lds[];
  const int NT = KK / 64;

  int nbn = N >> 8, nbm = M >> 8, nwg = nbm * nbn;
  int tid = threadIdx.x;
  int w = tid >> 6, lane = tid & 63;
  int wm = w >> 2, wn = w & 3;

  int rAoff = (wm * 128 + (lane & 15)) << 6;
  int rBoff = (wn * 64 + (lane & 15)) << 6;
  int hi8 = (lane >> 4) << 3, key8 = (lane & 7) << 3;
  int c0 = hi8 ^ key8;
  int c1 = (32 | hi8) ^ key8;
  int rowoff = w * 16 + (lane >> 3);
  int soff = ((lane & 7) ^ (lane >> 3)) << 3;

  bf16x8 a[8][2], b[4][2];
  f32x4 acc[8][4];

  int t = blockIdx.x;
  int m0, n0;
  TILE_COORD(t, m0, n0);
  const u16* pAg = A + (size_t)(m0 + rowoff) * KK + soff;
  const u16* pBg = Bt + (size_t)(n0 + rowoff) * KK + soff;

  // prologue: A(0),B(0) -> buf0; A(1) -> buf1 (left in flight)
  STAGE_A2(0, pAg, 0); STAGE_A2(1, pAg, 0);
  STAGE_B2(0, pBg, 0); STAGE_B2(1, pBg, 0);
  STAGE_A2(0, pAg + 64, 1); STAGE_A2(1, pAg + 64, 1);
  asm volatile("s_waitcnt vmcnt(4)");
  __builtin_amdgcn_s_barrier();
  ZERO_ACC;

  for (;;) {
    int tn = t + gridDim.x;
    bool last = tn >= nwg;
    const u16 *pAgN, *pBgN;
    int m0N = m0, n0N = n0;
    if (last) {                 // dummy: re-stage own tile start (L2-hot)
      pAgN = pAg; pBgN = pBg;
    } else {
      TILE_COORD(tn, m0N, n0N);
      pAgN = A + (size_t)(m0N + rowoff) * KK + soff;
      pBgN = Bt + (size_t)(n0N + rowoff) * KK + soff;
    }

    for (int k = 0; k < NT; k += 2) {
      const u16* bS1 = pBg + (k + 1) * 64;   // k+1 <= NT-1 always
      const u16* aS2 = (k + 2 < NT) ? pAg + (k + 2) * 64 : pAgN + (k + 2 - NT) * 64;
      TBX(0, bS1, aS2)
      const u16* bS2 = (k + 2 < NT) ? pBg + (k + 2) * 64 : pBgN + (k + 2 - NT) * 64;
      const u16* aS3 = (k + 3 < NT) ? pAg + (k + 3) * 64 : pAgN + (k + 3 - NT) * 64;
      TBX(1, bS2, aS3)
    }

    EPI(m0, n0);
    if (last) break;
    t = tn; m0 = m0N; n0 = n0N; pAg = pAgN; pBg = pBgN;
    ZERO_ACC;
  }
  asm volatile("s_waitcnt vmcnt(0) lgkmcnt(0)");  // drain dummy LDS-DMA
}

// ---------------- block-diagonal attention v3 (R7, best measured) ----------------
// 2048 WGs: (b,h,blk,half). 512 threads = 8 waves, 16 q-rows/wave.

__global__ __launch_bounds__(512, 4) void k_attn3(const u16* __restrict__ qkv,
                                                  u16* __restrict__ o) {
  __shared__ u16 ldsK[256 * 64];   // swizzled K rows
  __shared__ u16 ldsV[64 * 256];   // V^T [d][t] swizzled

  int bid = blockIdx.x;
  int g = ((bid & 7) << 8) | (bid >> 3);   // nwg = 2048, bijective XCD swizzle
  int hq = g & 1, blk = (g >> 1) & 15, h = (g >> 5) & 15, b = g >> 9;

  int tid = threadIdx.x;
  int w = tid >> 6, lane = tid & 63;
  int hgrp = lane >> 4;
  size_t rowb = ((size_t)(b * 4096 + blk * 256)) * 3072 + (size_t)h * 192;

  // Q fragment (B-operand; col = lane&15 = q-in-set, k = d contiguous 8)
  int qrow = hq * 128 + w * 16 + (lane & 15);
  const u16* qp = qkv + rowb + (size_t)qrow * 3072 + hgrp * 8;
  bf16x8 qf0 = *(const bf16x8*)(qp);
  bf16x8 qf1 = *(const bf16x8*)(qp + 32);

  // ---- stage K (async, pre-swizzled source) ----
#pragma unroll
  for (int it = 0; it < 4; ++it) {
    int trow = it * 64 + (tid >> 3);
    const u16* ksrc = qkv + rowb + (size_t)trow * 3072 + 64 +
                      (((lane & 7) ^ (lane >> 3)) << 3);
    async_ld16(ksrc, ldsK + (it * 64 + w * 8) * 64);
  }

  // ---- stage V^T vectorized: thread = (4 t-rows) x (8 d-cols) ----
  {
    int tg = tid >> 3, d0 = (tid & 7) << 3;
    const u16* vsrc = qkv + rowb + (size_t)(4 * tg) * 3072 + 128 + d0;
    union { uint4 v; u16 s[8]; } r0, r1, r2, r3;
    r0.v = *(const uint4*)(vsrc);
    r1.v = *(const uint4*)(vsrc + 3072);
    r2.v = *(const uint4*)(vsrc + 6144);
    r3.v = *(const uint4*)(vsrc + 9216);
    int gb = ((tg >> 1) << 4) + ((tg & 1) << 3);   // byte col of 4-t group
#pragma unroll
    for (int c = 0; c < 8; ++c) {
      int d = d0 + c;
      int key = (((d & 7) ^ ((d >> 3) & 7)) & 7) << 4;
      u64 pack = (u64)r0.s[c] | ((u64)r1.s[c] << 16) |
                 ((u64)r2.s[c] << 32) | ((u64)r3.s[c] << 48);
      *(u64*)((char*)ldsV + d * 512 + ((gb & ~15) ^ key) + (gb & 8)) = pack;
    }
  }
  __syncthreads();

  // ---- S^T = K Q : acc[ct] rows t=ct*16+4h'+reg, col q=lane&15 ----
  f32x4 acc0[16] = {};
  int cb = hgrp << 4;
#pragma unroll
  for (int ct = 0; ct < 16; ++ct) {
    int krow = ct * 16 + (lane & 15);
    const char* kb = (const char*)ldsK + krow * 128;
    int key = (krow & 7) << 4;
    bf16x8 k0 = *(const bf16x8*)(kb + (cb ^ key));
    bf16x8 k1 = *(const bf16x8*)(kb + ((64 + cb) ^ key));
    acc0[ct] = __builtin_amdgcn_mfma_f32_16x16x32_bf16(k0, qf0, acc0[ct], 0, 0, 0);
    acc0[ct] = __builtin_amdgcn_mfma_f32_16x16x32_bf16(k1, qf1, acc0[ct], 0, 0, 0);
  }

  // ---- softmax over t (in-lane 64 + xor16 + xor32) ----
  const float SC = 0.125f * 1.44269504f;
  float rden0;
  {
    float mx = -1e30f;
#pragma unroll
    for (int ct = 0; ct < 16; ++ct)
#pragma unroll
      for (int rg = 0; rg < 4; ++rg) mx = fmaxf(mx, acc0[ct][rg]);
    mx = fmaxf(mx, __shfl_xor(mx, 16));
    mx = fmaxf(mx, __shfl_xor(mx, 32));
    float s = 0.f;
#pragma unroll
    for (int ct = 0; ct < 16; ++ct)
#pragma unroll
      for (int rg = 0; rg < 4; ++rg) {
        float p = exp2f((acc0[ct][rg] - mx) * SC);
        acc0[ct][rg] = p;
        s += p;
      }
    s += __shfl_xor(s, 16);
    s += __shfl_xor(s, 32);
    rden0 = 1.f / s;
  }

  // ---- O = P V  (inline P-conversion per kt) ----
  int s1 = (lane & 15) + ((lane >> 4) & 1) * 32;
  int s2 = s1 + 16;
  bool lo = (lane < 32);
  f32x4 oa[4] = {};
#pragma unroll
  for (int kt = 0; kt < 8; ++kt) {
    u32 wA0, wB0, wA1, wB1;
    asm("v_cvt_pk_bf16_f32 %0, %1, %2" : "=v"(wA0)
        : "v"(acc0[2 * kt][0]), "v"(acc0[2 * kt][1]));
    asm("v_cvt_pk_bf16_f32 %0, %1, %2" : "=v"(wB0)
        : "v"(acc0[2 * kt][2]), "v"(acc0[2 * kt][3]));
    asm("v_cvt_pk_bf16_f32 %0, %1, %2" : "=v"(wA1)
        : "v"(acc0[2 * kt + 1][0]), "v"(acc0[2 * kt + 1][1]));
    asm("v_cvt_pk_bf16_f32 %0, %1, %2" : "=v"(wB1)
        : "v"(acc0[2 * kt + 1][2]), "v"(acc0[2 * kt + 1][3]));
    u32 t0a = (u32)__shfl((int)wA0, s1), t0b = (u32)__shfl((int)wA1, s1);
    u32 t1a = (u32)__shfl((int)wB0, s1), t1b = (u32)__shfl((int)wB1, s1);
    u32 t2a = (u32)__shfl((int)wA0, s2), t2b = (u32)__shfl((int)wA1, s2);
    u32 t3a = (u32)__shfl((int)wB0, s2), t3b = (u32)__shfl((int)wB1, s2);
    union { u32 w[4]; bf16x8 v; } pu;
    pu.w[0] = lo ? t0a : t0b;
    pu.w[1] = lo ? t1a : t1b;
    pu.w[2] = lo ? t2a : t2b;
    pu.w[3] = lo ? t3a : t3b;
    bf16x8 pa = pu.v;
    int vkb = 2 * (kt * 32 + hgrp * 8);
#pragma unroll
    for (int nt = 0; nt < 4; ++nt) {
      int vd = nt * 16 + (lane & 15);
      int key = (((vd & 7) ^ ((vd >> 3) & 7)) & 7) << 4;
      bf16x8 vf = *(const bf16x8*)((char*)ldsV + vd * 512 + (vkb ^ key));
      oa[nt] = __builtin_amdgcn_mfma_f32_16x16x32_bf16(pa, vf, oa[nt], 0, 0, 0);
    }
  }

  // ---- epilogue: rows q = 4*hgrp+reg (within wave's 16), col d ----
  float rd0[4];
#pragma unroll
  for (int rg = 0; rg < 4; ++rg) rd0[rg] = __shfl(rden0, 4 * hgrp + rg, 16);
  size_t ob = ((size_t)(b * 4096 + blk * 256 + hq * 128 + w * 16)) * 1024 +
              (size_t)h * 64;
#pragma unroll
  for (int nt = 0; nt < 4; ++nt)
#pragma unroll
    for (int rg = 0; rg < 4; ++rg) {
      int col = nt * 16 + (lane & 15);
      o[ob + (size_t)(4 * hgrp + rg) * 1024 + col] = f2bf(oa[nt][rg] * rd0[rg]);
    }
}

// ---------------- launch ----------------

extern "C" void kernel_launch(void* const* d_in, const int* in_sizes, int n_in,
                              void* d_out, int out_size, void* d_ws, size_t ws_size,
                              hipStream_t stream) {
  (void)in_sizes; (void)n_in; (void)out_size; (void)ws_size;
  const float* x = (const float*)d_in[0];
  const float* Wqkv = (const float*)d_in[1];
  const float* bqkv = (const float*)d_in[2];
  const float* Wout = (const float*)d_in[3];
  const float* bout = (const float*)d_in[4];
  float* out = (float*)d_out;

  char* ws = (char*)d_ws;
  u16* xb    = (u16*)(ws + 0);
  u16* wqkvT = (u16*)(ws + 33554432);
  u16* woT   = (u16*)(ws + 39845888);
  u16* qkv   = (u16*)(ws + 41943040);
  u16* ob    = (u16*)(ws + 142606336);

  hipFuncSetAttribute(reinterpret_cast<const void*>(&k_gemm8<1, 1024>),
                      hipFuncAttributeMaxDynamicSharedMemorySize, 131072);
  hipFuncSetAttribute(reinterpret_cast<const void*>(&k_gemm8<0, 1024>),
                      hipFuncAttributeMaxDynamicSharedMemorySize, 131072);

  // fused prep: cvt x + transpose both weight matrices (1 launch)
  k_prep<<<12288, 256, 0, stream>>>(x, xb, Wqkv, wqkvT, Wout, woT);

  // qkv = x @ Wqkv + bqkv (bf16 out): 768 tiles, persistent over 256 WGs
  k_gemm8<1, 1024><<<256, 512, 131072, stream>>>(xb, wqkvT, bqkv, qkv, 16384, 3072);

  // block-diagonal attention: 2 WGs per (b,h,blk)
  k_attn3<<<2048, 512, 0, stream>>>(qkv, ob);

  // out = o @ Wout + bout (fp32 out): 256 tiles
  k_gemm8<0, 1024><<<256, 512, 131072, stream>>>(ob, woT, bout, out, 16384, 1024);
}

// Round 10
// 216.786 us; speedup vs baseline: 1.0424x; 1.0011x over previous
//
#include <hip/hip_runtime.h>

typedef unsigned int u32;
typedef unsigned long long u64;
typedef unsigned short u16;
typedef short bf16x8 __attribute__((ext_vector_type(8)));
typedef u16 u16x8 __attribute__((ext_vector_type(8)));
typedef float f32x4 __attribute__((ext_vector_type(4)));

// ---------------- helpers ----------------

__device__ __forceinline__ u16 f2bf(float f) {
  unsigned u = __float_as_uint(f);
  u += 0x7FFFu + ((u >> 16) & 1u);   // RNE
  return (u16)(u >> 16);
}

typedef const void __attribute__((address_space(1)))* gas_p;
typedef void __attribute__((address_space(3)))* las_p;

__device__ __forceinline__ void async_ld16(const void* g, void* l) {
  __builtin_amdgcn_global_load_lds((gas_p)g, (las_p)l, 16, 0, 0);
}

// ---------------- fused prep: x->bf16, Wqkv^T->bf16, Wout^T->bf16 ----------------

__global__ __launch_bounds__(256) void k_prep(const float* __restrict__ x,
                                              u16* __restrict__ xb,
                                              const float* __restrict__ Wqkv,
                                              u16* __restrict__ wqkvT,
                                              const float* __restrict__ Wout,
                                              u16* __restrict__ woT) {
  __shared__ u16 tsh[32][33];
  int bid = blockIdx.x;
  int tid = threadIdx.x;

  if (bid < 8192) {
    int i = bid * 256 + tid;
    const float4* p = (const float4*)x + (size_t)i * 2;
    float4 a = p[0], b = p[1];
    u16x8 o;
    o[0] = f2bf(a.x); o[1] = f2bf(a.y); o[2] = f2bf(a.z); o[3] = f2bf(a.w);
    o[4] = f2bf(b.x); o[5] = f2bf(b.y); o[6] = f2bf(b.z); o[7] = f2bf(b.w);
    *((u16x8*)xb + i) = o;
    return;
  }

  const float* in;
  u16* out;
  int R, Ncols, bx, by;
  if (bid < 11264) {
    int t = bid - 8192;
    in = Wqkv; out = wqkvT; R = 1024; Ncols = 3072;
    bx = t % 96; by = t / 96;
  } else {
    int t = bid - 11264;
    in = Wout; out = woT; R = 1024; Ncols = 1024;
    bx = t & 31; by = t >> 5;
  }
  int tx = tid & 31, ty = tid >> 5;
  int c0 = bx * 32, r0 = by * 32;
#pragma unroll
  for (int j = 0; j < 32; j += 8)
    tsh[ty + j][tx] = f2bf(in[(size_t)(r0 + ty + j) * Ncols + c0 + tx]);
  __syncthreads();
#pragma unroll
  for (int j = 0; j < 32; j += 8)
    out[(size_t)(c0 + ty + j) * R + r0 + tx] = tsh[tx][ty + j];
}

// ---------------- 256^2 bf16 GEMM (R7 4-phase schedule, best measured) ----------------

#define STAGE_A2(h_, src_, dd_) do {                                       \
    const u16* g_ = (src_) + (size_t)(h_) * 128 * KK;                      \
    u16* s_ = lds + (dd_) * 16384 + (((h_) * 128 + w * 16) << 6);          \
    async_ld16(g_, s_);                                                    \
    async_ld16(g_ + 8 * (size_t)KK, s_ + 512);                             \
  } while (0)

#define STAGE_B2(h_, src_, dd_) do {                                       \
    const u16* g_ = (src_) + (size_t)(h_) * 128 * KK;                      \
    u16* s_ = lds + 32768 + (dd_) * 16384 + (((h_) * 128 + w * 16) << 6);  \
    async_ld16(g_, s_);                                                    \
    async_ld16(g_ + 8 * (size_t)KK, s_ + 512);                             \
  } while (0)

// 16 MFMA: ks-outer -> 8 independent MFMAs between dependent pairs
#define MQUAD(M0, N0)                                                      \
    _Pragma("unroll") for (int ks = 0; ks < 2; ++ks)                       \
    _Pragma("unroll") for (int mm = 0; mm < 4; ++mm)                       \
    _Pragma("unroll") for (int nn = 0; nn < 2; ++nn)                       \
      acc[(M0) + mm][(N0) + nn] = __builtin_amdgcn_mfma_f32_16x16x32_bf16( \
          a[(M0) + mm][ks], b[(N0) + nn][ks], acc[(M0) + mm][(N0) + nn], 0, 0, 0);

#define TBX(d_, bS_, aS_)                                                  \
  {                                                                        \
    const int doA = (d_) * 16384, doB = 32768 + (d_) * 16384;              \
    _Pragma("unroll") for (int f = 0; f < 4; ++f) {                        \
      a[f][0] = *(const bf16x8*)(lds + doA + rAoff + f * 1024 + c0);       \
      a[f][1] = *(const bf16x8*)(lds + doA + rAoff + f * 1024 + c1);       \
    }                                                                      \
    _Pragma("unroll") for (int f = 0; f < 2; ++f) {                        \
      b[f][0] = *(const bf16x8*)(lds + doB + rBoff + f * 1024 + c0);       \
      b[f][1] = *(const bf16x8*)(lds + doB + rBoff + f * 1024 + c1);       \
    }                                                                      \
    STAGE_B2(0, bS_, (d_) ^ 1);                                            \
    asm volatile("s_waitcnt lgkmcnt(8)");                                  \
    __builtin_amdgcn_s_barrier();                                          \
    asm volatile("s_waitcnt lgkmcnt(0)");                                  \
    __builtin_amdgcn_s_setprio(1);                                         \
    MQUAD(0, 0)                                                            \
    __builtin_amdgcn_s_setprio(0);                                         \
    __builtin_amdgcn_s_barrier();                                          \
    _Pragma("unroll") for (int f = 4; f < 8; ++f) {                        \
      a[f][0] = *(const bf16x8*)(lds + doA + rAoff + f * 1024 + c0);       \
      a[f][1] = *(const bf16x8*)(lds + doA + rAoff + f * 1024 + c1);       \
    }                                                                      \
    STAGE_B2(1, bS_, (d_) ^ 1);                                            \
    __builtin_amdgcn_s_barrier();                                          \
    asm volatile("s_waitcnt lgkmcnt(0)");                                  \
    __builtin_amdgcn_s_setprio(1);                                         \
    MQUAD(4, 0)                                                            \
    __builtin_amdgcn_s_setprio(0);                                         \
    __builtin_amdgcn_s_barrier();                                          \
    _Pragma("unroll") for (int f = 2; f < 4; ++f) {                        \
      b[f][0] = *(const bf16x8*)(lds + doB + rBoff + f * 1024 + c0);       \
      b[f][1] = *(const bf16x8*)(lds + doB + rBoff + f * 1024 + c1);       \
    }                                                                      \
    STAGE_A2(0, aS_, (d_));                                                \
    __builtin_amdgcn_s_barrier();                                          \
    asm volatile("s_waitcnt lgkmcnt(0)");                                  \
    __builtin_amdgcn_s_setprio(1);                                         \
    MQUAD(4, 2)                                                            \
    __builtin_amdgcn_s_setprio(0);                                         \
    __builtin_amdgcn_s_barrier();                                          \
    STAGE_A2(1, aS_, (d_));                                                \
    __builtin_amdgcn_s_setprio(1);                                         \
    MQUAD(0, 2)                                                            \
    __builtin_amdgcn_s_setprio(0);                                         \
    asm volatile("s_waitcnt vmcnt(4)");                                    \
    __builtin_amdgcn_s_barrier();                                          \
  }

#define EPI(PM0, PN0) do {                                                      \
    int ccol0 = (PN0) + wn * 64 + (lane & 15);                                  \
    float bv0 = bias[ccol0], bv1 = bias[ccol0 + 16];                            \
    float bv2 = bias[ccol0 + 32], bv3 = bias[ccol0 + 48];                       \
    size_t crow0 = (size_t)((PM0) + wm * 128 + ((lane >> 4) << 2));             \
    _Pragma("unroll") for (int m = 0; m < 8; ++m)                               \
    _Pragma("unroll") for (int reg = 0; reg < 4; ++reg) {                       \
      size_t ro = (crow0 + m * 16 + reg) * (size_t)N + ccol0;                   \
      float v0 = acc[m][0][reg] + bv0, v1 = acc[m][1][reg] + bv1;               \
      float v2 = acc[m][2][reg] + bv2, v3 = acc[m][3][reg] + bv3;               \
      if (OUT_BF16) {                                                           \
        ((u16*)Cout)[ro] = f2bf(v0); ((u16*)Cout)[ro + 16] = f2bf(v1);          \
        ((u16*)Cout)[ro + 32] = f2bf(v2); ((u16*)Cout)[ro + 48] = f2bf(v3);     \
      } else {                                                                  \
        ((float*)Cout)[ro] = v0; ((float*)Cout)[ro + 16] = v1;                  \
        ((float*)Cout)[ro + 32] = v2; ((float*)Cout)[ro + 48] = v3;             \
      }                                                                         \
    }                                                                           \
  } while (0)

#define TILE_COORD(tt, mm0, nn0) do {                                           \
    int q_ = nwg >> 3, r_ = nwg & 7, x_ = (tt) & 7, loc_ = (tt) >> 3;           \
    int swz_ = (x_ < r_ ? x_ * (q_ + 1) : r_ * (q_ + 1) + (x_ - r_) * q_) + loc_;\
    mm0 = (swz_ / nbn) << 8; nn0 = (swz_ % nbn) << 8;                           \
  } while (0)

#define ZERO_ACC do {                                                           \
    _Pragma("unroll") for (int m = 0; m < 8; ++m)                               \
    _Pragma("unroll") for (int n = 0; n < 4; ++n)                               \
      acc[m][n] = (f32x4){0.f, 0.f, 0.f, 0.f};                                  \
  } while (0)

template <int OUT_BF16, int KK>
__global__ __launch_bounds__(512, 2) void k_gemm8(const u16* __restrict__ A,
                                                  const u16* __restrict__ Bt,
                                                  const float* __restrict__ bias,
                                                  void* __restrict__ Cout,
                                                  int M, int N) {
  extern __shared__ u16 lds[];
  const int NT = KK / 64;

  int nbn = N >> 8, nbm = M >> 8, nwg = nbm * nbn;
  int tid = threadIdx.x;
  int w = tid >> 6, lane = tid & 63;
  int wm = w >> 2, wn = w & 3;

  int rAoff = (wm * 128 + (lane & 15)) << 6;
  int rBoff = (wn * 64 + (lane & 15)) << 6;
  int hi8 = (lane >> 4) << 3, key8 = (lane & 7) << 3;
  int c0 = hi8 ^ key8;
  int c1 = (32 | hi8) ^ key8;
  int rowoff = w * 16 + (lane >> 3);
  int soff = ((lane & 7) ^ (lane >> 3)) << 3;

  bf16x8 a[8][2], b[4][2];
  f32x4 acc[8][4];

  int t = blockIdx.x;
  int m0, n0;
  TILE_COORD(t, m0, n0);
  const u16* pAg = A + (size_t)(m0 + rowoff) * KK + soff;
  const u16* pBg = Bt + (size_t)(n0 + rowoff) * KK + soff;

  // prologue: A(0),B(0) -> buf0; A(1) -> buf1 (left in flight)
  STAGE_A2(0, pAg, 0); STAGE_A2(1, pAg, 0);
  STAGE_B2(0, pBg, 0); STAGE_B2(1, pBg, 0);
  STAGE_A2(0, pAg + 64, 1); STAGE_A2(1, pAg + 64, 1);
  asm volatile("s_waitcnt vmcnt(4)");
  __builtin_amdgcn_s_barrier();
  ZERO_ACC;

  for (;;) {
    int tn = t + gridDim.x;
    bool last = tn >= nwg;
    const u16 *pAgN, *pBgN;
    int m0N = m0, n0N = n0;
    if (last) {                 // dummy: re-stage own tile start (L2-hot)
      pAgN = pAg; pBgN = pBg;
    } else {
      TILE_COORD(tn, m0N, n0N);
      pAgN = A + (size_t)(m0N + rowoff) * KK + soff;
      pBgN = Bt + (size_t)(n0N + rowoff) * KK + soff;
    }

    for (int k = 0; k < NT; k += 2) {
      const u16* bS1 = pBg + (k + 1) * 64;   // k+1 <= NT-1 always
      const u16* aS2 = (k + 2 < NT) ? pAg + (k + 2) * 64 : pAgN + (k + 2 - NT) * 64;
      TBX(0, bS1, aS2)
      const u16* bS2 = (k + 2 < NT) ? pBg + (k + 2) * 64 : pBgN + (k + 2 - NT) * 64;
      const u16* aS3 = (k + 3 < NT) ? pAg + (k + 3) * 64 : pAgN + (k + 3 - NT) * 64;
      TBX(1, bS2, aS3)
    }

    EPI(m0, n0);
    if (last) break;
    t = tn; m0 = m0N; n0 = n0N; pAg = pAgN; pBg = pBgN;
    ZERO_ACC;
  }
  asm volatile("s_waitcnt vmcnt(0) lgkmcnt(0)");  // drain dummy LDS-DMA
}

// ---------------- block-diagonal attention v3 (R7, best measured) ----------------

__global__ __launch_bounds__(512, 4) void k_attn3(const u16* __restrict__ qkv,
                                                  u16* __restrict__ o) {
  __shared__ u16 ldsK[256 * 64];   // swizzled K rows
  __shared__ u16 ldsV[64 * 256];   // V^T [d][t] swizzled

  int bid = blockIdx.x;
  int g = ((bid & 7) << 8) | (bid >> 3);   // nwg = 2048, bijective XCD swizzle
  int hq = g & 1, blk = (g >> 1) & 15, h = (g >> 5) & 15, b = g >> 9;

  int tid = threadIdx.x;
  int w = tid >> 6, lane = tid & 63;
  int hgrp = lane >> 4;
  size_t rowb = ((size_t)(b * 4096 + blk * 256)) * 3072 + (size_t)h * 192;

  // Q fragment (B-operand; col = lane&15 = q-in-set, k = d contiguous 8)
  int qrow = hq * 128 + w * 16 + (lane & 15);
  const u16* qp = qkv + rowb + (size_t)qrow * 3072 + hgrp * 8;
  bf16x8 qf0 = *(const bf16x8*)(qp);
  bf16x8 qf1 = *(const bf16x8*)(qp + 32);

  // ---- stage K (async, pre-swizzled source) ----
#pragma unroll
  for (int it = 0; it < 4; ++it) {
    int trow = it * 64 + (tid >> 3);
    const u16* ksrc = qkv + rowb + (size_t)trow * 3072 + 64 +
                      (((lane & 7) ^ (lane >> 3)) << 3);
    async_ld16(ksrc, ldsK + (it * 64 + w * 8) * 64);
  }

  // ---- stage V^T vectorized: thread = (4 t-rows) x (8 d-cols) ----
  {
    int tg = tid >> 3, d0 = (tid & 7) << 3;
    const u16* vsrc = qkv + rowb + (size_t)(4 * tg) * 3072 + 128 + d0;
    union { uint4 v; u16 s[8]; } r0, r1, r2, r3;
    r0.v = *(const uint4*)(vsrc);
    r1.v = *(const uint4*)(vsrc + 3072);
    r2.v = *(const uint4*)(vsrc + 6144);
    r3.v = *(const uint4*)(vsrc + 9216);
    int gb = ((tg >> 1) << 4) + ((tg & 1) << 3);   // byte col of 4-t group
#pragma unroll
    for (int c = 0; c < 8; ++c) {
      int d = d0 + c;
      int key = (((d & 7) ^ ((d >> 3) & 7)) & 7) << 4;
      u64 pack = (u64)r0.s[c] | ((u64)r1.s[c] << 16) |
                 ((u64)r2.s[c] << 32) | ((u64)r3.s[c] << 48);
      *(u64*)((char*)ldsV + d * 512 + ((gb & ~15) ^ key) + (gb & 8)) = pack;
    }
  }
  __syncthreads();

  // ---- S^T = K Q : acc[ct] rows t=ct*16+4h'+reg, col q=lane&15 ----
  f32x4 acc0[16] = {};
  int cb = hgrp << 4;
#pragma unroll
  for (int ct = 0; ct < 16; ++ct) {
    int krow = ct * 16 + (lane & 15);
    const char* kb = (const char*)ldsK + krow * 128;
    int key = (krow & 7) << 4;
    bf16x8 k0 = *(const bf16x8*)(kb + (cb ^ key));
    bf16x8 k1 = *(const bf16x8*)(kb + ((64 + cb) ^ key));
    acc0[ct] = __builtin_amdgcn_mfma_f32_16x16x32_bf16(k0, qf0, acc0[ct], 0, 0, 0);
    acc0[ct] = __builtin_amdgcn_mfma_f32_16x16x32_bf16(k1, qf1, acc0[ct], 0, 0, 0);
  }

  // ---- softmax over t (in-lane 64 + xor16 + xor32) ----
  const float SC = 0.125f * 1.44269504f;
  float rden0;
  {
    float mx = -1e30f;
#pragma unroll
    for (int ct = 0; ct < 16; ++ct)
#pragma unroll
      for (int rg = 0; rg < 4; ++rg) mx = fmaxf(mx, acc0[ct][rg]);
    mx = fmaxf(mx, __shfl_xor(mx, 16));
    mx = fmaxf(mx, __shfl_xor(mx, 32));
    float s = 0.f;
#pragma unroll
    for (int ct = 0; ct < 16; ++ct)
#pragma unroll
      for (int rg = 0; rg < 4; ++rg) {
        float p = exp2f((acc0[ct][rg] - mx) * SC);
        acc0[ct][rg] = p;
        s += p;
      }
    s += __shfl_xor(s, 16);
    s += __shfl_xor(s, 32);
    rden0 = 1.f / s;
  }

  // ---- O = P V  (inline P-conversion per kt) ----
  int s1 = (lane & 15) + ((lane >> 4) & 1) * 32;
  int s2 = s1 + 16;
  bool lo = (lane < 32);
  f32x4 oa[4] = {};
#pragma unroll
  for (int kt = 0; kt < 8; ++kt) {
    u32 wA0, wB0, wA1, wB1;
    asm("v_cvt_pk_bf16_f32 %0, %1, %2" : "=v"(wA0)
        : "v"(acc0[2 * kt][0]), "v"(acc0[2 * kt][1]));
    asm("v_cvt_pk_bf16_f32 %0, %1, %2" : "=v"(wB0)
        : "v"(acc0[2 * kt][2]), "v"(acc0[2 * kt][3]));
    asm("v_cvt_pk_bf16_f32 %0, %1, %2" : "=v"(wA1)
        : "v"(acc0[2 * kt + 1][0]), "v"(acc0[2 * kt + 1][1]));
    asm("v_cvt_pk_bf16_f32 %0, %1, %2" : "=v"(wB1)
        : "v"(acc0[2 * kt + 1][2]), "v"(acc0[2 * kt + 1][3]));
    u32 t0a = (u32)__shfl((int)wA0, s1), t0b = (u32)__shfl((int)wA1, s1);
    u32 t1a = (u32)__shfl((int)wB0, s1), t1b = (u32)__shfl((int)wB1, s1);
    u32 t2a = (u32)__shfl((int)wA0, s2), t2b = (u32)__shfl((int)wA1, s2);
    u32 t3a = (u32)__shfl((int)wB0, s2), t3b = (u32)__shfl((int)wB1, s2);
    union { u32 w[4]; bf16x8 v; } pu;
    pu.w[0] = lo ? t0a : t0b;
    pu.w[1] = lo ? t1a : t1b;
    pu.w[2] = lo ? t2a : t2b;
    pu.w[3] = lo ? t3a : t3b;
    bf16x8 pa = pu.v;
    int vkb = 2 * (kt * 32 + hgrp * 8);
#pragma unroll
    for (int nt = 0; nt < 4; ++nt) {
      int vd = nt * 16 + (lane & 15);
      int key = (((vd & 7) ^ ((vd >> 3) & 7)) & 7) << 4;
      bf16x8 vf = *(const bf16x8*)((char*)ldsV + vd * 512 + (vkb ^ key));
      oa[nt] = __builtin_amdgcn_mfma_f32_16x16x32_bf16(pa, vf, oa[nt], 0, 0, 0);
    }
  }

  // ---- epilogue: rows q = 4*hgrp+reg (within wave's 16), col d ----
  float rd0[4];
#pragma unroll
  for (int rg = 0; rg < 4; ++rg) rd0[rg] = __shfl(rden0, 4 * hgrp + rg, 16);
  size_t ob = ((size_t)(b * 4096 + blk * 256 + hq * 128 + w * 16)) * 1024 +
              (size_t)h * 64;
#pragma unroll
  for (int nt = 0; nt < 4; ++nt)
#pragma unroll
    for (int rg = 0; rg < 4; ++rg) {
      int col = nt * 16 + (lane & 15);
      o[ob + (size_t)(4 * hgrp + rg) * 1024 + col] = f2bf(oa[nt][rg] * rd0[rg]);
    }
}

// ---------------- launch ----------------

extern "C" void kernel_launch(void* const* d_in, const int* in_sizes, int n_in,
                              void* d_out, int out_size, void* d_ws, size_t ws_size,
                              hipStream_t stream) {
  (void)in_sizes; (void)n_in; (void)out_size; (void)ws_size;
  const float* x = (const float*)d_in[0];
  const float* Wqkv = (const float*)d_in[1];
  const float* bqkv = (const float*)d_in[2];
  const float* Wout = (const float*)d_in[3];
  const float* bout = (const float*)d_in[4];
  float* out = (float*)d_out;

  char* ws = (char*)d_ws;
  u16* xb    = (u16*)(ws + 0);
  u16* wqkvT = (u16*)(ws + 33554432);
  u16* woT   = (u16*)(ws + 39845888);
  u16* qkv   = (u16*)(ws + 41943040);
  u16* ob    = (u16*)(ws + 142606336);

  hipFuncSetAttribute(reinterpret_cast<const void*>(&k_gemm8<1, 1024>),
                      hipFuncAttributeMaxDynamicSharedMemorySize, 131072);
  hipFuncSetAttribute(reinterpret_cast<const void*>(&k_gemm8<0, 1024>),
                      hipFuncAttributeMaxDynamicSharedMemorySize, 131072);

  // fused prep: cvt x + transpose both weight matrices (1 launch)
  k_prep<<<12288, 256, 0, stream>>>(x, xb, Wqkv, wqkvT, Wout, woT);

  // qkv = x @ Wqkv + bqkv (bf16 out): 768 tiles, persistent over 256 WGs
  k_gemm8<1, 1024><<<256, 512, 131072, stream>>>(xb, wqkvT, bqkv, qkv, 16384, 3072);

  // block-diagonal attention: 2 WGs per (b,h,blk)
  k_attn3<<<2048, 512, 0, stream>>>(qkv, ob);

  // out = o @ Wout + bout (fp32 out): 256 tiles
  k_gemm8<0, 1024><<<256, 512, 131072, stream>>>(ob, woT, bout, out, 16384, 1024);
}